// Round 1
// baseline (862.054 us; speedup 1.0000x reference)
//
#include <hip/hip_runtime.h>
#include <hip/hip_fp16.h>
#include <cstdint>
#include <cstddef>

#define BB 128
#define SS 256
#define LL 10
#define NTAGS 32
#define TAG_START 30
#define TAG_END 31
#define WDIM 100
#define CDIM 30
#define NFILT 30
#define HDIM 100
#define KIN 130      // LSTM_IN = WDIM + FILT
#define KPAD 160     // padded K for f16 GEMM operands
#define GDIM 400     // 4*H
#define NROWS 832    // 13*64 padded W rows
#define NEGV -10000.0f
#define CTOK 8       // tokens per charconv block

// fused-pre block ranges
#define NB_CONV (BB * SS / CTOK)               // 4096
#define NB_WORD (BB * SS * KPAD / 256)         // 20480
#define NB_WCVT (NROWS * KPAD / 256)           // 520
#define NB_PRE  (NB_CONV + NB_WORD + NB_WCVT)  // 25096

typedef _Float16 h2 __attribute__((ext_vector_type(2)));
typedef _Float16 f16x8 __attribute__((ext_vector_type(8)));
typedef float f32x4 __attribute__((ext_vector_type(4)));

__device__ __forceinline__ float sigm(float x) { return 1.0f / (1.0f + __expf(-x)); }
__device__ __forceinline__ float tanh_fast(float x) { return 2.0f / (1.0f + __expf(-2.0f * x)) - 1.0f; }

// lgkm-only barrier (R15-proven): leaves global prefetch/store in flight.
__device__ __forceinline__ void barrier_lds_only() {
  asm volatile("s_waitcnt lgkmcnt(0)" ::: "memory");
  __builtin_amdgcn_s_barrier();
  asm volatile("" ::: "memory");
}

// ---------------- K1 fused: charconv | word gather | wcvt, by block range ----------------
__global__ __launch_bounds__(256) void k_pre(
    const float* __restrict__ wemb, const int* __restrict__ wx,
    const float* __restrict__ cemb, const float* __restrict__ convw,
    const float* __restrict__ convb, const int* __restrict__ cx,
    const float* __restrict__ wihF, const float* __restrict__ wihB,
    _Float16* __restrict__ x16, _Float16* __restrict__ w16,
    float* __restrict__ out) {
  int blk = blockIdx.x;
  int tid = threadIdx.x;
  if (blk == 0 && tid == 0) out[0] = 0.f;

  if (blk < NB_CONV) {
    int tok8 = tid >> 5;
    int f = tid & 31;
    int token0 = blk * CTOK;
    __shared__ float e[CTOK][LL * CDIM];
    __shared__ float cw[NFILT * 3 * CDIM];   // 2700 floats = 10.8 KB
    __shared__ float cb[NFILT];
    __shared__ int ci[CTOK][LL];
    if (tid < CTOK * LL) {
      int t = tid / LL, l = tid - t * LL;
      ci[t][l] = cx[(token0 + t) * LL + l];
    }
    for (int i = tid; i < NFILT * 3 * CDIM; i += 256) cw[i] = convw[i];
    if (tid < NFILT) cb[tid] = convb[tid];
    __syncthreads();
    for (int i = tid; i < CTOK * LL * CDIM; i += 256) {
      int t = i / (LL * CDIM);
      int r = i - t * (LL * CDIM);
      int l = r / CDIM, c = r - l * CDIM;
      e[t][l * CDIM + c] = cemb[ci[t][l] * CDIM + c];
    }
    __syncthreads();
    if (f < NFILT) {
      float d0[LL], d1[LL], d2[LL];
#pragma unroll
      for (int l = 0; l < LL; l++) { d0[l] = 0.f; d1[l] = 0.f; d2[l] = 0.f; }
      const float* et = &e[tok8][0];
      for (int c = 0; c < CDIM; c++) {
        float w0 = cw[(f * 3 + 0) * CDIM + c];
        float w1 = cw[(f * 3 + 1) * CDIM + c];
        float w2 = cw[(f * 3 + 2) * CDIM + c];
#pragma unroll
        for (int l = 0; l < LL; l++) {
          float ev = et[l * CDIM + c];
          d0[l] += ev * w0; d1[l] += ev * w1; d2[l] += ev * w2;
        }
      }
      float bias = cb[f];
      float m = -3.0e38f;
#pragma unroll
      for (int h = 0; h < LL + 2; h++) {
        float acc = bias;
        int j0 = h - 2, j1 = h - 1, j2 = h;
        if (j0 >= 0 && j0 < LL) acc += d0[j0];
        if (j1 >= 0 && j1 < LL) acc += d1[j1];
        if (j2 >= 0 && j2 < LL) acc += d2[j2];
        m = fmaxf(m, acc);
      }
      x16[(size_t)(token0 + tok8) * KPAD + WDIM + f] = (_Float16)m;
    }
  } else if (blk < NB_CONV + NB_WORD) {
    int idx = (blk - NB_CONV) * 256 + tid;
    int token = idx / KPAD;
    int d = idx - token * KPAD;
    if (d < WDIM) {
      x16[idx] = (_Float16)wemb[(size_t)wx[token] * WDIM + d];
    } else if (d >= KIN) {
      x16[idx] = (_Float16)0.f;
    }
  } else {
    int idx = (blk - NB_CONV - NB_WORD) * 256 + tid;
    int n = idx / KPAD;
    int k = idx - n * KPAD;
    float v = 0.f;
    if (k < KIN && n < 2 * GDIM) {
      v = (n < GDIM) ? wihF[(size_t)n * KIN + k] : wihB[(size_t)(n - GDIM) * KIN + k];
    }
    w16[idx] = (_Float16)v;
  }
}

// ---------------- K2: pre = x @ wih^T + (bih+bhh), MFMA f16, f16 output ----------------
// R19 delta: pre is now stored TRANSPOSED-blocked as [n(400)][t(256)][b(128)]
// so k_lstm can load 4 consecutive batches per gate as one b64 and feed them
// straight into the MFMA C operand. Same store count (16 scalar b16, similar
// scatter as before), bias math unchanged.
__global__ __launch_bounds__(256) void k_pregemm(
    const _Float16* __restrict__ x16, const _Float16* __restrict__ w16,
    const float* __restrict__ bihF, const float* __restrict__ bhhF,
    const float* __restrict__ bihB, const float* __restrict__ bhhB,
    _Float16* __restrict__ preF, _Float16* __restrict__ preB) {
  __shared__ __align__(16) _Float16 Asl[64 * 40];
  __shared__ __align__(16) _Float16 Bsl[64 * 40];
  int m0 = blockIdx.x * 64;
  int n0 = blockIdx.y * 64;
  int tid = threadIdx.x;
  int lane = tid & 63, w = tid >> 6;
  int quad = lane >> 4, l15 = lane & 15;

  f32x4 acc[4];
#pragma unroll
  for (int i = 0; i < 4; i++) acc[i] = (f32x4){0.f, 0.f, 0.f, 0.f};

  int r = tid >> 2;            // staging row 0..63
  int kk = (tid & 3) * 8;      // k offset within chunk
  const _Float16* xs = x16 + (size_t)(m0 + r) * KPAD + kk;
  const _Float16* wsrc = w16 + (size_t)(n0 + r) * KPAD + kk;

  for (int kc = 0; kc < 5; kc++) {
    if (kc) __syncthreads();
    *(f16x8*)&Asl[r * 40 + kk] = *(const f16x8*)(xs + kc * 32);
    *(f16x8*)&Bsl[r * 40 + kk] = *(const f16x8*)(wsrc + kc * 32);
    __syncthreads();

    f16x8 bfrag = *(const f16x8*)&Bsl[(w * 16 + l15) * 40 + quad * 8];
#pragma unroll
    for (int mt = 0; mt < 4; mt++) {
      f16x8 afrag = *(const f16x8*)&Asl[(mt * 16 + l15) * 40 + quad * 8];
      acc[mt] = __builtin_amdgcn_mfma_f32_16x16x32_f16(afrag, bfrag, acc[mt], 0, 0, 0);
    }
  }

  int ng = n0 + w * 16 + l15;  // this lane's output column (fixed)
  if (ng < 2 * GDIM) {
    int dir = ng >= GDIM;
    int jb = dir ? ng - GDIM : ng;
    _Float16* dst = dir ? preB : preF;
    float bias = (dir ? bihB : bihF)[jb] + (dir ? bhhB : bhhF)[jb];
#pragma unroll
    for (int mt = 0; mt < 4; mt++) {
#pragma unroll
      for (int i = 0; i < 4; i++) {
        int m = m0 + mt * 16 + quad * 4 + i;  // token = b*SS + t
        dst[((size_t)jb * SS + (m & (SS - 1))) * BB + (m >> 8)] =
            (_Float16)(acc[mt][i] + bias);
      }
    }
  }
}

// ---------------- K3: recurrent LSTM scan — MFMA-batched (R19 rewrite) ----------------
// 16 chains (batches) per block, 16 blocks (8 per direction). Per step the
// h@whh^T matvec is one real GEMM: M=16 batches, N=400 gates, K=100(pad128),
// via mfma_f32_16x16x32_f16 with whh held entirely in registers (B-frags).
// Gate-major tiling: wave w owns j in [16w,16w+16) for ALL 4 gates, so each
// lane ends the MFMA holding i/f/g/o for its 4 cells in its own acc regs:
// no gate-reduce, no gpart LDS round-trip, activation dense on 64 lanes.
// pre (transposed [n][t][b]) is b64-loaded per gate and used to INIT the
// MFMA C operand. One lgkm-only barrier per step (double-buffered h in LDS).
// hA uses a T2-style XOR swizzle (idx = m*128 + (k ^ ((m&7)<<3))) making the
// A-frag ds_read_b128 pattern hit all 8 16B slots uniformly (conflict-free).
#define MB 16   // batches per block
__global__ __launch_bounds__(448) void k_lstm(
    const _Float16* __restrict__ preF, const _Float16* __restrict__ preB,
    const float* __restrict__ whhF, const float* __restrict__ whhB,
    _Float16* __restrict__ hbuf) {
  int blk = blockIdx.x;              // 16 blocks
  int dir = blk >> 3;                // 0 fwd, 1 bwd
  int b0 = (blk & 7) * MB;
  const _Float16* pre = dir ? preB : preF;
  const float* whh = dir ? whhB : whhF;
  int tid = threadIdx.x;
  int w = tid >> 6;                  // wave 0..6 -> j-tile
  int lane = tid & 63;
  int l15 = lane & 15, q = lane >> 4;
  int j = w * 16 + l15;              // this lane's hidden column (may be >= 100)
  bool jv = (j < HDIM);
  int jc = jv ? j : 0;               // clamped for safe addressing

  // ---- B-frag preload: wfrag[g][kc] = whh[g*100+j][kc*32 + q*8 .. +7], f16
  f16x8 wfrag[4][4];
#pragma unroll
  for (int g = 0; g < 4; g++) {
#pragma unroll
    for (int kc = 0; kc < 4; kc++) {
      float tmp[8] = {0.f, 0.f, 0.f, 0.f, 0.f, 0.f, 0.f, 0.f};
      if (jv) {
        const float* wr = whh + (size_t)(g * HDIM + j) * HDIM;
#pragma unroll
        for (int hh = 0; hh < 2; hh++) {
          int kk = kc * 32 + q * 8 + hh * 4;
          if (kk < HDIM) {   // kk max valid start is 96 -> covers 96..99
            float4 v = *(const float4*)(wr + kk);
            tmp[hh * 4 + 0] = v.x; tmp[hh * 4 + 1] = v.y;
            tmp[hh * 4 + 2] = v.z; tmp[hh * 4 + 3] = v.w;
          }
        }
      }
      f16x8 fr;
#pragma unroll
      for (int e = 0; e < 8; e++) fr[e] = (_Float16)tmp[e];
      wfrag[g][kc] = fr;
    }
  }

  // ---- h double-buffer in LDS, XOR-swizzled rows of 128 halves ----
  __shared__ __align__(16) _Float16 hA[2][MB * 128];
  for (int idx = tid; idx < 2 * MB * 128; idx += 448) hA[0][idx] = (_Float16)0.f;

  float cst[4] = {0.f, 0.f, 0.f, 0.f};

  // ---- pre pointers: layout [n=400][t=256][b=128], walk t in scan order ----
  int t0 = dir ? (SS - 1) : 0;
  const int tstep = dir ? -BB : BB;
  const _Float16* pg[4];
  uint2 p0[4], p1[4];
#pragma unroll
  for (int g = 0; g < 4; g++)
    pg[g] = pre + ((size_t)(g * HDIM + jc) * SS + t0) * BB + b0 + q * 4;
  __syncthreads();   // hA zero-init visible
#pragma unroll
  for (int g = 0; g < 4; g++) { p0[g] = *(const uint2*)pg[g]; pg[g] += tstep; }
#pragma unroll
  for (int g = 0; g < 4; g++) { p1[g] = *(const uint2*)pg[g]; pg[g] += tstep; }

  int cur = 0;
  for (int step = 0; step <= SS; step++) {
    // -- phase 1: coalesced global store of h(step-1) from hA[cur] --
    if (step > 0 && tid < 400) {
      int m = tid / 25, c4 = tid - m * 25;
      int hidx = m * 128 + ((c4 * 4) ^ ((m & 7) << 3));
      uint2 hv = *(const uint2*)&hA[cur][hidx];
      int tprev = dir ? (SS - step) : (step - 1);
      *(uint2*)&hbuf[((size_t)(b0 + m) * SS + tprev) * (2 * HDIM) + dir * HDIM + c4 * 4] = hv;
    }
    if (step == SS) break;

    // -- phase 2: A-frags from hA[cur] (h of previous step; zeros at step 0) --
    f16x8 af[4];
#pragma unroll
    for (int kc = 0; kc < 4; kc++) {
      int off = kc * 32 + q * 8;
      af[kc] = *(const f16x8*)&hA[cur][l15 * 128 + (off ^ ((l15 & 7) << 3))];
    }

    // -- phase 3: prefetch pre for step+2 (stays in workspace even past end) --
    uint2 p2[4];
#pragma unroll
    for (int g = 0; g < 4; g++) { p2[g] = *(const uint2*)pg[g]; pg[g] += tstep; }

    // -- phase 4: C init from pre, then 16 MFMAs (4 gates x 4 k-chunks) --
    f32x4 acc[4];
#pragma unroll
    for (int g = 0; g < 4; g++) {
      h2 lo = __builtin_bit_cast(h2, p0[g].x);
      h2 hi = __builtin_bit_cast(h2, p0[g].y);
      acc[g] = (f32x4){(float)lo.x, (float)lo.y, (float)hi.x, (float)hi.y};
    }
#pragma unroll
    for (int kc = 0; kc < 4; kc++) {
#pragma unroll
      for (int g = 0; g < 4; g++) {
        acc[g] = __builtin_amdgcn_mfma_f32_16x16x32_f16(af[kc], wfrag[g][kc], acc[g], 0, 0, 0);
      }
    }

    // -- phase 5: activations (dense: every lane owns 4 cells), h -> hA[cur^1] --
    int nbuf = cur ^ 1;
    if (jv) {
#pragma unroll
      for (int i = 0; i < 4; i++) {
        float gi = acc[0][i], gf = acc[1][i], gg = acc[2][i], go = acc[3][i];
        float ig = sigm(gi), fg = sigm(gf), g2 = tanh_fast(gg), og = sigm(go);
        cst[i] = fg * cst[i] + ig * g2;
        float h = og * tanh_fast(cst[i]);
        int m = q * 4 + i;
        hA[nbuf][m * 128 + (j ^ ((m & 7) << 3))] = (_Float16)h;
      }
    }

    barrier_lds_only();
    cur ^= 1;
#pragma unroll
    for (int g = 0; g < 4; g++) { p0[g] = p1[g]; p1[g] = p2[g]; }
  }
}

// ---------------- K4: emission = [h_f,h_b] @ proj_w^T + proj_b ----------------
__global__ __launch_bounds__(256) void k_proj(const _Float16* __restrict__ hbuf,
                                              const float* __restrict__ pw,
                                              const float* __restrict__ pb,
                                              float* __restrict__ em) {
  __shared__ __align__(16) float pws[NTAGS * 204];   // 25.9 KB
  __shared__ float pbs[NTAGS];
  int tid = threadIdx.x;
  for (int i = tid; i < NTAGS * 2 * HDIM; i += 256) {
    int tag = i / (2 * HDIM);
    int k = i - tag * (2 * HDIM);
    pws[tag * 204 + k] = pw[i];
  }
  if (tid < NTAGS) pbs[tid] = pb[tid];
  __syncthreads();

  int idx = blockIdx.x * blockDim.x + tid;  // token*32 + tag
  if (idx >= BB * SS * NTAGS) return;
  int token = idx >> 5, tag = idx & 31;
  const uint4* h4 = (const uint4*)(hbuf + (size_t)token * 2 * HDIM);
  const float4* w4 = (const float4*)&pws[tag * 204];
  float acc = pbs[tag];
#pragma unroll
  for (int k = 0; k < 25; k++) {
    uint4 hv = h4[k];
    h2 a = __builtin_bit_cast(h2, hv.x);
    h2 bq = __builtin_bit_cast(h2, hv.y);
    h2 cq = __builtin_bit_cast(h2, hv.z);
    h2 d = __builtin_bit_cast(h2, hv.w);
    float4 w0 = w4[k * 2], w1 = w4[k * 2 + 1];
    acc += (float)a.x * w0.x + (float)a.y * w0.y + (float)bq.x * w0.z + (float)bq.y * w0.w
         + (float)cq.x * w1.x + (float)cq.y * w1.y + (float)d.x * w1.z + (float)d.y * w1.w;
  }
  em[idx] = acc;
}

// ---------------- K5: CRF forward + gold score + loss, wave-synchronous ----------------
__global__ __launch_bounds__(64) void k_crf(const float* __restrict__ em,
                                            const float* __restrict__ trans,
                                            const int* __restrict__ mask,
                                            const int* __restrict__ y,
                                            float* __restrict__ out) {
  int b = blockIdx.x;
  int lane = threadIdx.x;
  int j = lane & 31;
  int h = lane >> 5;

  // ---- gold path score, 64 lanes ----
  float sacc = 0.f;
  for (int s = lane; s < SS; s += 64) {
    int curt = y[b * SS + s];
    int prevt = (s == 0) ? TAG_START : y[b * SS + s - 1];
    float mk = (float)mask[b * SS + s];
    sacc += (em[((size_t)b * SS + s) * NTAGS + curt] + trans[prevt * NTAGS + curt]) * mk;
  }
#pragma unroll
  for (int off = 32; off > 0; off >>= 1) sacc += __shfl_down(sacc, off);
  float scoreYv = __shfl(sacc, 0) + trans[y[b * SS + SS - 1] * NTAGS + TAG_END];

  float tcol[16];
#pragma unroll
  for (int i = 0; i < 16; i++) tcol[i] = trans[(h * 16 + i) * NTAGS + j];

  float la = (j == TAG_START) ? 0.f : NEGV;

  const float* emb = em + (size_t)b * SS * NTAGS + j;
  const int* mkb = mask + b * SS;
  float e0 = emb[0], e1 = emb[NTAGS];
  int m0i = mkb[0], m1i = mkb[1];

  for (int s = 0; s < SS; s++) {
    int sn = (s + 2 < SS) ? (s + 2) : (SS - 1);
    float e2 = emb[(size_t)sn * NTAGS];
    int m2i = mkb[sn];

    float v[16];
#pragma unroll
    for (int i = 0; i < 16; i++) v[i] = __shfl(la, h * 16 + i) + tcol[i];

    float ma = v[0], mb2 = v[1];
#pragma unroll
    for (int i = 2; i < 16; i += 2) { ma = fmaxf(ma, v[i]); mb2 = fmaxf(mb2, v[i + 1]); }
    float mh = fmaxf(ma, mb2);
    float m = fmaxf(mh, __shfl_xor(mh, 32));

    float sa = 0.f, sb = 0.f;
#pragma unroll
    for (int i = 0; i < 16; i += 2) { sa += __expf(v[i] - m); sb += __expf(v[i + 1] - m); }
    float sh = sa + sb;
    float sum = sh + __shfl_xor(sh, 32);

    float la2 = m + __logf(sum) + e0;
    float mk = (float)m0i;
    la = la2 * mk + la * (1.f - mk);
    e0 = e1; e1 = e2; m0i = m1i; m1i = m2i;
  }
  la += trans[j * NTAGS + TAG_END];

  float mm = la;
#pragma unroll
  for (int off = 16; off > 0; off >>= 1) mm = fmaxf(mm, __shfl_xor(mm, off));
  float ss = __expf(la - mm);
#pragma unroll
  for (int off = 16; off > 0; off >>= 1) ss += __shfl_xor(ss, off);
  float total = mm + __logf(ss);
  if (lane == 0) atomicAdd(out, (total - scoreYv) * (1.0f / BB));
}

extern "C" void kernel_launch(void* const* d_in, const int* in_sizes, int n_in,
                              void* d_out, int out_size, void* d_ws, size_t ws_size,
                              hipStream_t stream) {
  const float* word_emb = (const float*)d_in[0];
  const float* char_emb = (const float*)d_in[1];
  const float* conv_w   = (const float*)d_in[2];
  const float* conv_b   = (const float*)d_in[3];
  const float* wih_f    = (const float*)d_in[4];
  const float* whh_f    = (const float*)d_in[5];
  const float* bih_f    = (const float*)d_in[6];
  const float* bhh_f    = (const float*)d_in[7];
  const float* wih_b    = (const float*)d_in[8];
  const float* whh_b    = (const float*)d_in[9];
  const float* bih_b    = (const float*)d_in[10];
  const float* bhh_b    = (const float*)d_in[11];
  const float* proj_w   = (const float*)d_in[12];
  const float* proj_b   = (const float*)d_in[13];
  const float* trans    = (const float*)d_in[14];
  const int* word_x     = (const int*)d_in[15];
  const int* char_x     = (const int*)d_in[16];
  const int* y          = (const int*)d_in[17];
  const int* mask       = (const int*)d_in[18];
  float* out = (float*)d_out;

  _Float16* x16   = (_Float16*)d_ws;                     // 32768*160 halves
  _Float16* w16   = x16 + (size_t)BB * SS * KPAD;        // 832*160 halves
  _Float16* preF  = w16 + (size_t)NROWS * KPAD;          // 400*256*128 halves (transposed [n][t][b])
  _Float16* preB  = preF + (size_t)BB * SS * GDIM;       // 400*256*128 halves
  _Float16* hbuf  = preB + (size_t)BB * SS * GDIM;       // 32768*200 halves
  float* em       = (float*)(hbuf + (size_t)BB * SS * 2 * HDIM);  // 32768*32 f32

  k_pre<<<NB_PRE, 256, 0, stream>>>(word_emb, word_x, char_emb, conv_w, conv_b,
                                    char_x, wih_f, wih_b, x16, w16, out);
  k_pregemm<<<dim3(BB * SS / 64, 13), 256, 0, stream>>>(x16, w16, bih_f, bhh_f,
                                                        bih_b, bhh_b, preF, preB);
  k_lstm<<<16, 448, 0, stream>>>(preF, preB, whh_f, whh_b, hbuf);
  k_proj<<<(BB * SS * NTAGS + 255) / 256, 256, 0, stream>>>(hbuf, proj_w, proj_b, em);
  k_crf<<<BB, 64, 0, stream>>>(em, trans, mask, y, out);
}

// Round 2
// 537.405 us; speedup vs baseline: 1.6041x; 1.6041x over previous
//
#include <hip/hip_runtime.h>
#include <hip/hip_fp16.h>
#include <cstdint>
#include <cstddef>

#define BB 128
#define SS 256
#define LL 10
#define NTAGS 32
#define TAG_START 30
#define TAG_END 31
#define WDIM 100
#define CDIM 30
#define NFILT 30
#define HDIM 100
#define KIN 130      // LSTM_IN = WDIM + FILT
#define KPAD 160     // padded K for f16 GEMM operands
#define GDIM 400     // 4*H
#define NROWS 832    // 13*64 padded W rows
#define NEGV -10000.0f
#define CTOK 8       // tokens per charconv block

// fused-pre block ranges
#define NB_CONV (BB * SS / CTOK)               // 4096
#define NB_WORD (BB * SS * KPAD / 256)         // 20480
#define NB_WCVT (NROWS * KPAD / 256)           // 520
#define NB_PRE  (NB_CONV + NB_WORD + NB_WCVT)  // 25096

typedef _Float16 h2 __attribute__((ext_vector_type(2)));
typedef _Float16 f16x8 __attribute__((ext_vector_type(8)));
typedef float f32x4 __attribute__((ext_vector_type(4)));

__device__ __forceinline__ float sigm(float x) { return 1.0f / (1.0f + __expf(-x)); }
__device__ __forceinline__ float tanh_fast(float x) { return 2.0f / (1.0f + __expf(-2.0f * x)) - 1.0f; }

// lgkm-only barrier (R15-proven): leaves global prefetch/store in flight.
__device__ __forceinline__ void barrier_lds_only() {
  asm volatile("s_waitcnt lgkmcnt(0)" ::: "memory");
  __builtin_amdgcn_s_barrier();
  asm volatile("" ::: "memory");
}

// ---------------- K1 fused: charconv | word gather | wcvt, by block range ----------------
__global__ __launch_bounds__(256) void k_pre(
    const float* __restrict__ wemb, const int* __restrict__ wx,
    const float* __restrict__ cemb, const float* __restrict__ convw,
    const float* __restrict__ convb, const int* __restrict__ cx,
    const float* __restrict__ wihF, const float* __restrict__ wihB,
    _Float16* __restrict__ x16, _Float16* __restrict__ w16,
    float* __restrict__ out) {
  int blk = blockIdx.x;
  int tid = threadIdx.x;
  if (blk == 0 && tid == 0) out[0] = 0.f;

  if (blk < NB_CONV) {
    int tok8 = tid >> 5;
    int f = tid & 31;
    int token0 = blk * CTOK;
    __shared__ float e[CTOK][LL * CDIM];
    __shared__ float cw[NFILT * 3 * CDIM];   // 2700 floats = 10.8 KB
    __shared__ float cb[NFILT];
    __shared__ int ci[CTOK][LL];
    if (tid < CTOK * LL) {
      int t = tid / LL, l = tid - t * LL;
      ci[t][l] = cx[(token0 + t) * LL + l];
    }
    for (int i = tid; i < NFILT * 3 * CDIM; i += 256) cw[i] = convw[i];
    if (tid < NFILT) cb[tid] = convb[tid];
    __syncthreads();
    for (int i = tid; i < CTOK * LL * CDIM; i += 256) {
      int t = i / (LL * CDIM);
      int r = i - t * (LL * CDIM);
      int l = r / CDIM, c = r - l * CDIM;
      e[t][l * CDIM + c] = cemb[ci[t][l] * CDIM + c];
    }
    __syncthreads();
    if (f < NFILT) {
      float d0[LL], d1[LL], d2[LL];
#pragma unroll
      for (int l = 0; l < LL; l++) { d0[l] = 0.f; d1[l] = 0.f; d2[l] = 0.f; }
      const float* et = &e[tok8][0];
      for (int c = 0; c < CDIM; c++) {
        float w0 = cw[(f * 3 + 0) * CDIM + c];
        float w1 = cw[(f * 3 + 1) * CDIM + c];
        float w2 = cw[(f * 3 + 2) * CDIM + c];
#pragma unroll
        for (int l = 0; l < LL; l++) {
          float ev = et[l * CDIM + c];
          d0[l] += ev * w0; d1[l] += ev * w1; d2[l] += ev * w2;
        }
      }
      float bias = cb[f];
      float m = -3.0e38f;
#pragma unroll
      for (int h = 0; h < LL + 2; h++) {
        float acc = bias;
        int j0 = h - 2, j1 = h - 1, j2 = h;
        if (j0 >= 0 && j0 < LL) acc += d0[j0];
        if (j1 >= 0 && j1 < LL) acc += d1[j1];
        if (j2 >= 0 && j2 < LL) acc += d2[j2];
        m = fmaxf(m, acc);
      }
      x16[(size_t)(token0 + tok8) * KPAD + WDIM + f] = (_Float16)m;
    }
  } else if (blk < NB_CONV + NB_WORD) {
    int idx = (blk - NB_CONV) * 256 + tid;
    int token = idx / KPAD;
    int d = idx - token * KPAD;
    if (d < WDIM) {
      x16[idx] = (_Float16)wemb[(size_t)wx[token] * WDIM + d];
    } else if (d >= KIN) {
      x16[idx] = (_Float16)0.f;
    }
  } else {
    int idx = (blk - NB_CONV - NB_WORD) * 256 + tid;
    int n = idx / KPAD;
    int k = idx - n * KPAD;
    float v = 0.f;
    if (k < KIN && n < 2 * GDIM) {
      v = (n < GDIM) ? wihF[(size_t)n * KIN + k] : wihB[(size_t)(n - GDIM) * KIN + k];
    }
    w16[idx] = (_Float16)v;
  }
}

// ---------------- K2: pre = x @ wih^T + (bih+bhh), MFMA f16, f16 output ----------------
// Reverted to the proven row-major output layout: pre[token][400].
__global__ __launch_bounds__(256) void k_pregemm(
    const _Float16* __restrict__ x16, const _Float16* __restrict__ w16,
    const float* __restrict__ bihF, const float* __restrict__ bhhF,
    const float* __restrict__ bihB, const float* __restrict__ bhhB,
    _Float16* __restrict__ preF, _Float16* __restrict__ preB) {
  __shared__ __align__(16) _Float16 Asl[64 * 40];
  __shared__ __align__(16) _Float16 Bsl[64 * 40];
  int m0 = blockIdx.x * 64;
  int n0 = blockIdx.y * 64;
  int tid = threadIdx.x;
  int lane = tid & 63, w = tid >> 6;
  int quad = lane >> 4, l15 = lane & 15;

  f32x4 acc[4];
#pragma unroll
  for (int i = 0; i < 4; i++) acc[i] = (f32x4){0.f, 0.f, 0.f, 0.f};

  int r = tid >> 2;            // staging row 0..63
  int kk = (tid & 3) * 8;      // k offset within chunk
  const _Float16* xs = x16 + (size_t)(m0 + r) * KPAD + kk;
  const _Float16* wsrc = w16 + (size_t)(n0 + r) * KPAD + kk;

  for (int kc = 0; kc < 5; kc++) {
    if (kc) __syncthreads();
    *(f16x8*)&Asl[r * 40 + kk] = *(const f16x8*)(xs + kc * 32);
    *(f16x8*)&Bsl[r * 40 + kk] = *(const f16x8*)(wsrc + kc * 32);
    __syncthreads();

    f16x8 bfrag = *(const f16x8*)&Bsl[(w * 16 + l15) * 40 + quad * 8];
#pragma unroll
    for (int mt = 0; mt < 4; mt++) {
      f16x8 afrag = *(const f16x8*)&Asl[(mt * 16 + l15) * 40 + quad * 8];
      acc[mt] = __builtin_amdgcn_mfma_f32_16x16x32_f16(afrag, bfrag, acc[mt], 0, 0, 0);
    }
  }

  int ng = n0 + w * 16 + l15;  // this lane's output column (fixed)
  if (ng < 2 * GDIM) {
    int dir = ng >= GDIM;
    int jb = dir ? ng - GDIM : ng;
    _Float16* dst = dir ? preB : preF;
    float bias = (dir ? bihB : bihF)[jb] + (dir ? bhhB : bhhF)[jb];
#pragma unroll
    for (int mt = 0; mt < 4; mt++) {
#pragma unroll
      for (int i = 0; i < 4; i++) {
        int m = m0 + mt * 16 + quad * 4 + i;
        dst[(size_t)m * GDIM + jb] = (_Float16)(acc[mt][i] + bias);
      }
    }
  }
}

// ---------------- K3: recurrent LSTM scan (R20 rewrite: pair-per-cell) ----------------
// 256 blocks (one chain each), 256 threads (4 waves). Thread t: cell j = t>>1,
// k-half kh = t&1. Each lane computes partial dots for ALL 4 gates of its cell
// over 50 of the 100 k values; the pair-reduce is a single same-wave
// __shfl_xor(.,1) -> no cross-wave gpart LDS round-trip, ONE barrier per step.
// whh lives entirely in registers (wp[4][25] half2, loaded once). h is
// double-buffered in 512 B of LDS; all reads are same-address broadcasts
// (conflict-free). pre is added pre-reduce from 2 prefetched b16 loads/lane.
__global__ __launch_bounds__(256, 1) void k_lstm(
    const _Float16* __restrict__ preF, const _Float16* __restrict__ preB,
    const float* __restrict__ whhF, const float* __restrict__ whhB,
    _Float16* __restrict__ hbuf) {
  int blk = blockIdx.x;              // 256 blocks
  int dir = blk >> 7;                // 0 fwd, 1 bwd
  int b = blk & 127;
  const _Float16* pre = dir ? preB : preF;
  const float* whh = dir ? whhB : whhF;
  int tid = threadIdx.x;
  int j = tid >> 1;                  // cell 0..127 (valid < 100)
  int kh = tid & 1;                  // k-half: [0,50) or [50,100)
  bool act = (j < HDIM);
  int jc = act ? j : 0;

  // ---- weight preload: wp[g][q] = whh[g*100+j][kh*50 + 2q .. +1] as half2 ----
  __half2 wp[4][25];
#pragma unroll
  for (int g = 0; g < 4; g++) {
    const float* wr = whh + (size_t)(g * HDIM + jc) * HDIM + kh * 50;
#pragma unroll
    for (int q = 0; q < 25; q++) {
      wp[g][q] = __floats2half2_rn(wr[2 * q], wr[2 * q + 1]);
    }
  }

  // ---- h double buffer: [buf][seg][64 halves], segs are the two k-halves ----
  __shared__ __align__(16) _Float16 hsh[2][2][64];   // 512 B
  if (tid < 128) ((int*)hsh)[tid] = 0;
  float c = 0.f;

  // ---- pre base: layout [token][400], token = b*SS + t ----
  int t0 = dir ? (SS - 1) : 0;
  const intptr_t pstep = dir ? -(intptr_t)GDIM : (intptr_t)GDIM;
  const _Float16* pbase = pre + ((size_t)b * SS + t0) * GDIM + kh * 200 + jc;
  _Float16 pa0 = pbase[0], pb0 = pbase[100];
  _Float16 pa1 = pbase[pstep], pb1 = pbase[pstep + 100];
  __syncthreads();   // hsh zero-init visible

  int cur = 0;
  for (int s = 0; s < SS; s++) {
    // prefetch pre for step s+2 (clamped; stays in workspace)
    int sn = (s + 2 < SS) ? (s + 2) : (SS - 1);
    const _Float16* pn = pbase + (intptr_t)sn * pstep;
    _Float16 pa2 = pn[0], pb2 = pn[100];

    // h of previous step: 50 halves of this lane's k-half (broadcast reads)
    const _Float16* hseg = &hsh[cur][kh][0];
    uint4 hv0 = *(const uint4*)(hseg);
    uint4 hv1 = *(const uint4*)(hseg + 8);
    uint4 hv2 = *(const uint4*)(hseg + 16);
    uint4 hv3 = *(const uint4*)(hseg + 24);
    uint4 hv4 = *(const uint4*)(hseg + 32);
    uint4 hv5 = *(const uint4*)(hseg + 40);
    uint32_t hv6 = *(const uint32_t*)(hseg + 48);
    __half2 hp[25];
    hp[0]  = __builtin_bit_cast(__half2, hv0.x);
    hp[1]  = __builtin_bit_cast(__half2, hv0.y);
    hp[2]  = __builtin_bit_cast(__half2, hv0.z);
    hp[3]  = __builtin_bit_cast(__half2, hv0.w);
    hp[4]  = __builtin_bit_cast(__half2, hv1.x);
    hp[5]  = __builtin_bit_cast(__half2, hv1.y);
    hp[6]  = __builtin_bit_cast(__half2, hv1.z);
    hp[7]  = __builtin_bit_cast(__half2, hv1.w);
    hp[8]  = __builtin_bit_cast(__half2, hv2.x);
    hp[9]  = __builtin_bit_cast(__half2, hv2.y);
    hp[10] = __builtin_bit_cast(__half2, hv2.z);
    hp[11] = __builtin_bit_cast(__half2, hv2.w);
    hp[12] = __builtin_bit_cast(__half2, hv3.x);
    hp[13] = __builtin_bit_cast(__half2, hv3.y);
    hp[14] = __builtin_bit_cast(__half2, hv3.z);
    hp[15] = __builtin_bit_cast(__half2, hv3.w);
    hp[16] = __builtin_bit_cast(__half2, hv4.x);
    hp[17] = __builtin_bit_cast(__half2, hv4.y);
    hp[18] = __builtin_bit_cast(__half2, hv4.z);
    hp[19] = __builtin_bit_cast(__half2, hv4.w);
    hp[20] = __builtin_bit_cast(__half2, hv5.x);
    hp[21] = __builtin_bit_cast(__half2, hv5.y);
    hp[22] = __builtin_bit_cast(__half2, hv5.z);
    hp[23] = __builtin_bit_cast(__half2, hv5.w);
    hp[24] = __builtin_bit_cast(__half2, hv6);

    // 4-gate partial dots over this lane's 50 k values
    float racc[4];
    __half2 z = __floats2half2_rn(0.f, 0.f);
#pragma unroll
    for (int g = 0; g < 4; g++) {
      __half2 a0 = z, a1 = z;
#pragma unroll
      for (int q = 0; q < 25; q += 2) a0 = __hfma2(wp[g][q], hp[q], a0);
#pragma unroll
      for (int q = 1; q < 25; q += 2) a1 = __hfma2(wp[g][q], hp[q], a1);
      racc[g] = (__low2float(a0) + __high2float(a0)) +
                (__low2float(a1) + __high2float(a1));
    }

    // add pre (each lane of the pair contributes 2 gates), then pair-reduce
    if (kh == 0) { racc[0] += (float)pa0; racc[1] += (float)pb0; }
    else         { racc[2] += (float)pa0; racc[3] += (float)pb0; }
#pragma unroll
    for (int g = 0; g < 4; g++) racc[g] += __shfl_xor(racc[g], 1);

    // activations (both lanes of the pair compute identically; no divergence)
    float ig = sigm(racc[0]), fg = sigm(racc[1]);
    float g2 = tanh_fast(racc[2]), og = sigm(racc[3]);
    c = fg * c + ig * g2;
    float h = og * tanh_fast(c);

    if (act && kh == 0) {
      int seg = (j >= 50) ? 1 : 0;
      hsh[cur ^ 1][seg][j - seg * 50] = (_Float16)h;
      int t = dir ? (SS - 1 - s) : s;
      hbuf[((size_t)b * SS + t) * (2 * HDIM) + dir * HDIM + j] = (_Float16)h;
    }

    barrier_lds_only();
    cur ^= 1;
    pa0 = pa1; pb0 = pb1; pa1 = pa2; pb1 = pb2;
  }
}

// ---------------- K4: emission = [h_f,h_b] @ proj_w^T + proj_b ----------------
__global__ __launch_bounds__(256) void k_proj(const _Float16* __restrict__ hbuf,
                                              const float* __restrict__ pw,
                                              const float* __restrict__ pb,
                                              float* __restrict__ em) {
  __shared__ __align__(16) float pws[NTAGS * 204];   // 25.9 KB
  __shared__ float pbs[NTAGS];
  int tid = threadIdx.x;
  for (int i = tid; i < NTAGS * 2 * HDIM; i += 256) {
    int tag = i / (2 * HDIM);
    int k = i - tag * (2 * HDIM);
    pws[tag * 204 + k] = pw[i];
  }
  if (tid < NTAGS) pbs[tid] = pb[tid];
  __syncthreads();

  int idx = blockIdx.x * blockDim.x + tid;  // token*32 + tag
  if (idx >= BB * SS * NTAGS) return;
  int token = idx >> 5, tag = idx & 31;
  const uint4* h4 = (const uint4*)(hbuf + (size_t)token * 2 * HDIM);
  const float4* w4 = (const float4*)&pws[tag * 204];
  float acc = pbs[tag];
#pragma unroll
  for (int k = 0; k < 25; k++) {
    uint4 hv = h4[k];
    h2 a = __builtin_bit_cast(h2, hv.x);
    h2 bq = __builtin_bit_cast(h2, hv.y);
    h2 cq = __builtin_bit_cast(h2, hv.z);
    h2 d = __builtin_bit_cast(h2, hv.w);
    float4 w0 = w4[k * 2], w1 = w4[k * 2 + 1];
    acc += (float)a.x * w0.x + (float)a.y * w0.y + (float)bq.x * w0.z + (float)bq.y * w0.w
         + (float)cq.x * w1.x + (float)cq.y * w1.y + (float)d.x * w1.z + (float)d.y * w1.w;
  }
  em[idx] = acc;
}

// ---------------- K5: CRF forward + gold score + loss, wave-synchronous ----------------
__global__ __launch_bounds__(64) void k_crf(const float* __restrict__ em,
                                            const float* __restrict__ trans,
                                            const int* __restrict__ mask,
                                            const int* __restrict__ y,
                                            float* __restrict__ out) {
  int b = blockIdx.x;
  int lane = threadIdx.x;
  int j = lane & 31;
  int h = lane >> 5;

  // ---- gold path score, 64 lanes ----
  float sacc = 0.f;
  for (int s = lane; s < SS; s += 64) {
    int curt = y[b * SS + s];
    int prevt = (s == 0) ? TAG_START : y[b * SS + s - 1];
    float mk = (float)mask[b * SS + s];
    sacc += (em[((size_t)b * SS + s) * NTAGS + curt] + trans[prevt * NTAGS + curt]) * mk;
  }
#pragma unroll
  for (int off = 32; off > 0; off >>= 1) sacc += __shfl_down(sacc, off);
  float scoreYv = __shfl(sacc, 0) + trans[y[b * SS + SS - 1] * NTAGS + TAG_END];

  float tcol[16];
#pragma unroll
  for (int i = 0; i < 16; i++) tcol[i] = trans[(h * 16 + i) * NTAGS + j];

  float la = (j == TAG_START) ? 0.f : NEGV;

  const float* emb = em + (size_t)b * SS * NTAGS + j;
  const int* mkb = mask + b * SS;
  float e0 = emb[0], e1 = emb[NTAGS];
  int m0i = mkb[0], m1i = mkb[1];

  for (int s = 0; s < SS; s++) {
    int sn = (s + 2 < SS) ? (s + 2) : (SS - 1);
    float e2 = emb[(size_t)sn * NTAGS];
    int m2i = mkb[sn];

    float v[16];
#pragma unroll
    for (int i = 0; i < 16; i++) v[i] = __shfl(la, h * 16 + i) + tcol[i];

    float ma = v[0], mb2 = v[1];
#pragma unroll
    for (int i = 2; i < 16; i += 2) { ma = fmaxf(ma, v[i]); mb2 = fmaxf(mb2, v[i + 1]); }
    float mh = fmaxf(ma, mb2);
    float m = fmaxf(mh, __shfl_xor(mh, 32));

    float sa = 0.f, sb = 0.f;
#pragma unroll
    for (int i = 0; i < 16; i += 2) { sa += __expf(v[i] - m); sb += __expf(v[i + 1] - m); }
    float sh = sa + sb;
    float sum = sh + __shfl_xor(sh, 32);

    float la2 = m + __logf(sum) + e0;
    float mk = (float)m0i;
    la = la2 * mk + la * (1.f - mk);
    e0 = e1; e1 = e2; m0i = m1i; m1i = m2i;
  }
  la += trans[j * NTAGS + TAG_END];

  float mm = la;
#pragma unroll
  for (int off = 16; off > 0; off >>= 1) mm = fmaxf(mm, __shfl_xor(mm, off));
  float ss = __expf(la - mm);
#pragma unroll
  for (int off = 16; off > 0; off >>= 1) ss += __shfl_xor(ss, off);
  float total = mm + __logf(ss);
  if (lane == 0) atomicAdd(out, (total - scoreYv) * (1.0f / BB));
}

extern "C" void kernel_launch(void* const* d_in, const int* in_sizes, int n_in,
                              void* d_out, int out_size, void* d_ws, size_t ws_size,
                              hipStream_t stream) {
  const float* word_emb = (const float*)d_in[0];
  const float* char_emb = (const float*)d_in[1];
  const float* conv_w   = (const float*)d_in[2];
  const float* conv_b   = (const float*)d_in[3];
  const float* wih_f    = (const float*)d_in[4];
  const float* whh_f    = (const float*)d_in[5];
  const float* bih_f    = (const float*)d_in[6];
  const float* bhh_f    = (const float*)d_in[7];
  const float* wih_b    = (const float*)d_in[8];
  const float* whh_b    = (const float*)d_in[9];
  const float* bih_b    = (const float*)d_in[10];
  const float* bhh_b    = (const float*)d_in[11];
  const float* proj_w   = (const float*)d_in[12];
  const float* proj_b   = (const float*)d_in[13];
  const float* trans    = (const float*)d_in[14];
  const int* word_x     = (const int*)d_in[15];
  const int* char_x     = (const int*)d_in[16];
  const int* y          = (const int*)d_in[17];
  const int* mask       = (const int*)d_in[18];
  float* out = (float*)d_out;

  _Float16* x16   = (_Float16*)d_ws;                     // 32768*160 halves
  _Float16* w16   = x16 + (size_t)BB * SS * KPAD;        // 832*160 halves
  _Float16* preF  = w16 + (size_t)NROWS * KPAD;          // 32768*400 halves
  _Float16* preB  = preF + (size_t)BB * SS * GDIM;       // 32768*400 halves
  _Float16* hbuf  = preB + (size_t)BB * SS * GDIM;       // 32768*200 halves
  float* em       = (float*)(hbuf + (size_t)BB * SS * 2 * HDIM);  // 32768*32 f32

  k_pre<<<NB_PRE, 256, 0, stream>>>(word_emb, word_x, char_emb, conv_w, conv_b,
                                    char_x, wih_f, wih_b, x16, w16, out);
  k_pregemm<<<dim3(BB * SS / 64, 13), 256, 0, stream>>>(x16, w16, bih_f, bhh_f,
                                                        bih_b, bhh_b, preF, preB);
  k_lstm<<<256, 256, 0, stream>>>(preF, preB, whh_f, whh_b, hbuf);
  k_proj<<<(BB * SS * NTAGS + 255) / 256, 256, 0, stream>>>(hbuf, proj_w, proj_b, em);
  k_crf<<<BB, 64, 0, stream>>>(em, trans, mask, y, out);
}

// Round 3
// 495.203 us; speedup vs baseline: 1.7408x; 1.0852x over previous
//
#include <hip/hip_runtime.h>
#include <hip/hip_fp16.h>
#include <cstdint>
#include <cstddef>

#define BB 128
#define SS 256
#define LL 10
#define NTAGS 32
#define TAG_START 30
#define TAG_END 31
#define WDIM 100
#define CDIM 30
#define NFILT 30
#define HDIM 100
#define KIN 130      // LSTM_IN = WDIM + FILT
#define KPAD 160     // padded K for f16 GEMM operands
#define GDIM 400     // 4*H
#define NROWS 832    // 13*64 padded W rows
#define NEGV -10000.0f
#define CTOK 8       // tokens per charconv block

// fused-pre block ranges
#define NB_CONV (BB * SS / CTOK)               // 4096
#define NB_WORD (BB * SS * KPAD / 256)         // 20480
#define NB_WCVT (NROWS * KPAD / 256)           // 520
#define NB_PRE  (NB_CONV + NB_WORD + NB_WCVT)  // 25096

typedef _Float16 h2 __attribute__((ext_vector_type(2)));
typedef _Float16 f16x8 __attribute__((ext_vector_type(8)));
typedef float f32x4 __attribute__((ext_vector_type(4)));

#if __has_builtin(__builtin_amdgcn_fdot2)
#define HAVE_FDOT2 1
#else
#define HAVE_FDOT2 0
#endif

__device__ __forceinline__ float sigm(float x) { return 1.0f / (1.0f + __expf(-x)); }
__device__ __forceinline__ float tanh_fast(float x) { return 2.0f / (1.0f + __expf(-2.0f * x)) - 1.0f; }

// lgkm-only barrier (R15-proven): leaves global prefetch/store in flight.
__device__ __forceinline__ void barrier_lds_only() {
  asm volatile("s_waitcnt lgkmcnt(0)" ::: "memory");
  __builtin_amdgcn_s_barrier();
  asm volatile("" ::: "memory");
}

// ---------------- K1 fused: charconv | word gather | wcvt, by block range ----------------
__global__ __launch_bounds__(256) void k_pre(
    const float* __restrict__ wemb, const int* __restrict__ wx,
    const float* __restrict__ cemb, const float* __restrict__ convw,
    const float* __restrict__ convb, const int* __restrict__ cx,
    const float* __restrict__ wihF, const float* __restrict__ wihB,
    _Float16* __restrict__ x16, _Float16* __restrict__ w16,
    float* __restrict__ out) {
  int blk = blockIdx.x;
  int tid = threadIdx.x;
  if (blk == 0 && tid == 0) out[0] = 0.f;

  if (blk < NB_CONV) {
    int tok8 = tid >> 5;
    int f = tid & 31;
    int token0 = blk * CTOK;
    __shared__ float e[CTOK][LL * CDIM];
    __shared__ float cw[NFILT * 3 * CDIM];   // 2700 floats = 10.8 KB
    __shared__ float cb[NFILT];
    __shared__ int ci[CTOK][LL];
    if (tid < CTOK * LL) {
      int t = tid / LL, l = tid - t * LL;
      ci[t][l] = cx[(token0 + t) * LL + l];
    }
    for (int i = tid; i < NFILT * 3 * CDIM; i += 256) cw[i] = convw[i];
    if (tid < NFILT) cb[tid] = convb[tid];
    __syncthreads();
    for (int i = tid; i < CTOK * LL * CDIM; i += 256) {
      int t = i / (LL * CDIM);
      int r = i - t * (LL * CDIM);
      int l = r / CDIM, c = r - l * CDIM;
      e[t][l * CDIM + c] = cemb[ci[t][l] * CDIM + c];
    }
    __syncthreads();
    if (f < NFILT) {
      float d0[LL], d1[LL], d2[LL];
#pragma unroll
      for (int l = 0; l < LL; l++) { d0[l] = 0.f; d1[l] = 0.f; d2[l] = 0.f; }
      const float* et = &e[tok8][0];
      for (int c = 0; c < CDIM; c++) {
        float w0 = cw[(f * 3 + 0) * CDIM + c];
        float w1 = cw[(f * 3 + 1) * CDIM + c];
        float w2 = cw[(f * 3 + 2) * CDIM + c];
#pragma unroll
        for (int l = 0; l < LL; l++) {
          float ev = et[l * CDIM + c];
          d0[l] += ev * w0; d1[l] += ev * w1; d2[l] += ev * w2;
        }
      }
      float bias = cb[f];
      float m = -3.0e38f;
#pragma unroll
      for (int h = 0; h < LL + 2; h++) {
        float acc = bias;
        int j0 = h - 2, j1 = h - 1, j2 = h;
        if (j0 >= 0 && j0 < LL) acc += d0[j0];
        if (j1 >= 0 && j1 < LL) acc += d1[j1];
        if (j2 >= 0 && j2 < LL) acc += d2[j2];
        m = fmaxf(m, acc);
      }
      x16[(size_t)(token0 + tok8) * KPAD + WDIM + f] = (_Float16)m;
    }
  } else if (blk < NB_CONV + NB_WORD) {
    int idx = (blk - NB_CONV) * 256 + tid;
    int token = idx / KPAD;
    int d = idx - token * KPAD;
    if (d < WDIM) {
      x16[idx] = (_Float16)wemb[(size_t)wx[token] * WDIM + d];
    } else if (d >= KIN) {
      x16[idx] = (_Float16)0.f;
    }
  } else {
    int idx = (blk - NB_CONV - NB_WORD) * 256 + tid;
    int n = idx / KPAD;
    int k = idx - n * KPAD;
    float v = 0.f;
    if (k < KIN && n < 2 * GDIM) {
      v = (n < GDIM) ? wihF[(size_t)n * KIN + k] : wihB[(size_t)(n - GDIM) * KIN + k];
    }
    w16[idx] = (_Float16)v;
  }
}

// ---------------- K2: pre = x @ wih^T + (bih+bhh), MFMA f16, f16 output ----------------
__global__ __launch_bounds__(256) void k_pregemm(
    const _Float16* __restrict__ x16, const _Float16* __restrict__ w16,
    const float* __restrict__ bihF, const float* __restrict__ bhhF,
    const float* __restrict__ bihB, const float* __restrict__ bhhB,
    _Float16* __restrict__ preF, _Float16* __restrict__ preB) {
  __shared__ __align__(16) _Float16 Asl[64 * 40];
  __shared__ __align__(16) _Float16 Bsl[64 * 40];
  int m0 = blockIdx.x * 64;
  int n0 = blockIdx.y * 64;
  int tid = threadIdx.x;
  int lane = tid & 63, w = tid >> 6;
  int quad = lane >> 4, l15 = lane & 15;

  f32x4 acc[4];
#pragma unroll
  for (int i = 0; i < 4; i++) acc[i] = (f32x4){0.f, 0.f, 0.f, 0.f};

  int r = tid >> 2;            // staging row 0..63
  int kk = (tid & 3) * 8;      // k offset within chunk
  const _Float16* xs = x16 + (size_t)(m0 + r) * KPAD + kk;
  const _Float16* wsrc = w16 + (size_t)(n0 + r) * KPAD + kk;

  for (int kc = 0; kc < 5; kc++) {
    if (kc) __syncthreads();
    *(f16x8*)&Asl[r * 40 + kk] = *(const f16x8*)(xs + kc * 32);
    *(f16x8*)&Bsl[r * 40 + kk] = *(const f16x8*)(wsrc + kc * 32);
    __syncthreads();

    f16x8 bfrag = *(const f16x8*)&Bsl[(w * 16 + l15) * 40 + quad * 8];
#pragma unroll
    for (int mt = 0; mt < 4; mt++) {
      f16x8 afrag = *(const f16x8*)&Asl[(mt * 16 + l15) * 40 + quad * 8];
      acc[mt] = __builtin_amdgcn_mfma_f32_16x16x32_f16(afrag, bfrag, acc[mt], 0, 0, 0);
    }
  }

  int ng = n0 + w * 16 + l15;  // this lane's output column (fixed)
  if (ng < 2 * GDIM) {
    int dir = ng >= GDIM;
    int jb = dir ? ng - GDIM : ng;
    _Float16* dst = dir ? preB : preF;
    float bias = (dir ? bihB : bihF)[jb] + (dir ? bhhB : bhhF)[jb];
#pragma unroll
    for (int mt = 0; mt < 4; mt++) {
#pragma unroll
      for (int i = 0; i < 4; i++) {
        int m = m0 + mt * 16 + quad * 4 + i;
        dst[(size_t)m * GDIM + jb] = (_Float16)(acc[mt][i] + bias);
      }
    }
  }
}

// ---------------- K3: recurrent LSTM scan (R21: LDS-staged pre, no per-step global) ----------------
// R21 theory: R15 and R20 both landed at exactly 208 us despite different
// barrier/reduce structures -> the shared per-step global 'pre' load with the
// rolling-register prefetch (p0=p1;p1=p2) was the bottleneck: the register
// rotation forces a vmcnt wait on a load issued only ~1/3 step earlier,
// exposing ~L3/HBM latency EVERY step. Fix: stage pre in 32-step chunks into
// LDS (contiguous 25.6 KB global region -> perfectly coalesced); issue next
// chunk's loads right after this chunk's ds_writes; ONE vmcnt(0) per 32 steps.
// Per-step pre access becomes 2 ds_read_u16.
#define CH 32
#define NCH (SS / CH)
__global__ __launch_bounds__(256, 1) void k_lstm(
    const _Float16* __restrict__ preF, const _Float16* __restrict__ preB,
    const float* __restrict__ whhF, const float* __restrict__ whhB,
    _Float16* __restrict__ hbuf) {
  int blk = blockIdx.x;              // 256 blocks
  int dir = blk >> 7;                // 0 fwd, 1 bwd
  int b = blk & 127;
  const _Float16* pre = dir ? preB : preF;
  const float* whh = dir ? whhB : whhF;
  int tid = threadIdx.x;
  int j = tid >> 1;                  // cell 0..127 (valid < 100)
  int kh = tid & 1;                  // k-half: [0,50) or [50,100)
  bool act = (j < HDIM);
  int jc = act ? j : 0;

  // ---- weight preload: wp[g][q] = whh[g*100+j][kh*50 + 2q .. +1] as half2 ----
  __half2 wp[4][25];
#pragma unroll
  for (int g = 0; g < 4; g++) {
    const float* wr = whh + (size_t)(g * HDIM + jc) * HDIM + kh * 50;
#pragma unroll
    for (int q = 0; q < 25; q++) {
      wp[g][q] = __floats2half2_rn(wr[2 * q], wr[2 * q + 1]);
    }
  }

  // ---- LDS: pre chunk buffer (28.7 KB) + h double buffer (512 B) ----
  __shared__ __align__(16) _Float16 preS[14336];   // 1792 uint4
  __shared__ __align__(16) _Float16 hsh[2][2][64];
  if (tid < 128) ((int*)hsh)[tid] = 0;
  float c = 0.f;

  // chunk ck covers source rows tmin..tmin+31 (contiguous); copy 1792 uint4
  // (28672 B; slight overread stays inside the workspace).
  // dir=0: step s=ck*32+s2 -> row s2. dir=1: step s -> row 31-s2.
#define GSRC(ck) ((const uint4*)(pre + ((size_t)b * SS + (dir ? (SS - CH - (ck) * CH) : ((ck) * CH))) * GDIM))

  uint4 r0, r1, r2, r3, r4, r5, r6;
  {
    const uint4* s0 = GSRC(0);
    r0 = s0[0 * 256 + tid]; r1 = s0[1 * 256 + tid]; r2 = s0[2 * 256 + tid];
    r3 = s0[3 * 256 + tid]; r4 = s0[4 * 256 + tid]; r5 = s0[5 * 256 + tid];
    r6 = s0[6 * 256 + tid];
  }

  // rolling hbuf store pointer (strength-reduced)
  _Float16* hptr = hbuf + ((size_t)b * SS + (dir ? (SS - 1) : 0)) * (2 * HDIM) + dir * HDIM + jc;
  const intptr_t hstep = dir ? -(intptr_t)(2 * HDIM) : (intptr_t)(2 * HDIM);

  int cur = 0;
  for (int ck = 0; ck < NCH; ck++) {
    asm volatile("s_waitcnt vmcnt(0)" ::: "memory");   // staged regs landed
    *(uint4*)&preS[(0 * 256 + tid) * 8] = r0;
    *(uint4*)&preS[(1 * 256 + tid) * 8] = r1;
    *(uint4*)&preS[(2 * 256 + tid) * 8] = r2;
    *(uint4*)&preS[(3 * 256 + tid) * 8] = r3;
    *(uint4*)&preS[(4 * 256 + tid) * 8] = r4;
    *(uint4*)&preS[(5 * 256 + tid) * 8] = r5;
    *(uint4*)&preS[(6 * 256 + tid) * 8] = r6;
    if (ck + 1 < NCH) {
      const uint4* snx = GSRC(ck + 1);
      r0 = snx[0 * 256 + tid]; r1 = snx[1 * 256 + tid]; r2 = snx[2 * 256 + tid];
      r3 = snx[3 * 256 + tid]; r4 = snx[4 * 256 + tid]; r5 = snx[5 * 256 + tid];
      r6 = snx[6 * 256 + tid];
    }
    barrier_lds_only();   // preS (and hsh zeros on ck=0) visible to all waves

    int preOff = (dir ? (CH - 1) * GDIM : 0) + kh * 200 + jc;
    const int pdelta = dir ? -GDIM : GDIM;

    for (int s2 = 0; s2 < CH; s2++) {
      float paF = (float)preS[preOff];
      float pbF = (float)preS[preOff + 100];

      // h of previous step: 50 halves of this lane's k-half (broadcast reads)
      const _Float16* hseg = &hsh[cur][kh][0];
      uint4 hv0 = *(const uint4*)(hseg);
      uint4 hv1 = *(const uint4*)(hseg + 8);
      uint4 hv2 = *(const uint4*)(hseg + 16);
      uint4 hv3 = *(const uint4*)(hseg + 24);
      uint4 hv4 = *(const uint4*)(hseg + 32);
      uint4 hv5 = *(const uint4*)(hseg + 40);
      uint32_t hv6 = *(const uint32_t*)(hseg + 48);
      __half2 hp[25];
      hp[0]  = __builtin_bit_cast(__half2, hv0.x);
      hp[1]  = __builtin_bit_cast(__half2, hv0.y);
      hp[2]  = __builtin_bit_cast(__half2, hv0.z);
      hp[3]  = __builtin_bit_cast(__half2, hv0.w);
      hp[4]  = __builtin_bit_cast(__half2, hv1.x);
      hp[5]  = __builtin_bit_cast(__half2, hv1.y);
      hp[6]  = __builtin_bit_cast(__half2, hv1.z);
      hp[7]  = __builtin_bit_cast(__half2, hv1.w);
      hp[8]  = __builtin_bit_cast(__half2, hv2.x);
      hp[9]  = __builtin_bit_cast(__half2, hv2.y);
      hp[10] = __builtin_bit_cast(__half2, hv2.z);
      hp[11] = __builtin_bit_cast(__half2, hv2.w);
      hp[12] = __builtin_bit_cast(__half2, hv3.x);
      hp[13] = __builtin_bit_cast(__half2, hv3.y);
      hp[14] = __builtin_bit_cast(__half2, hv3.z);
      hp[15] = __builtin_bit_cast(__half2, hv3.w);
      hp[16] = __builtin_bit_cast(__half2, hv4.x);
      hp[17] = __builtin_bit_cast(__half2, hv4.y);
      hp[18] = __builtin_bit_cast(__half2, hv4.z);
      hp[19] = __builtin_bit_cast(__half2, hv4.w);
      hp[20] = __builtin_bit_cast(__half2, hv5.x);
      hp[21] = __builtin_bit_cast(__half2, hv5.y);
      hp[22] = __builtin_bit_cast(__half2, hv5.z);
      hp[23] = __builtin_bit_cast(__half2, hv5.w);
      hp[24] = __builtin_bit_cast(__half2, hv6);

      // 4-gate partial dots over this lane's 50 k values
      float racc[4];
#if HAVE_FDOT2
#pragma unroll
      for (int g = 0; g < 4; g++) {
        float a0 = 0.f, a1 = 0.f;
#pragma unroll
        for (int q = 0; q < 25; q += 2)
          a0 = __builtin_amdgcn_fdot2(__builtin_bit_cast(h2, wp[g][q]),
                                      __builtin_bit_cast(h2, hp[q]), a0, false);
#pragma unroll
        for (int q = 1; q < 25; q += 2)
          a1 = __builtin_amdgcn_fdot2(__builtin_bit_cast(h2, wp[g][q]),
                                      __builtin_bit_cast(h2, hp[q]), a1, false);
        racc[g] = a0 + a1;
      }
#else
      __half2 z = __floats2half2_rn(0.f, 0.f);
#pragma unroll
      for (int g = 0; g < 4; g++) {
        __half2 a0 = z, a1 = z;
#pragma unroll
        for (int q = 0; q < 25; q += 2) a0 = __hfma2(wp[g][q], hp[q], a0);
#pragma unroll
        for (int q = 1; q < 25; q += 2) a1 = __hfma2(wp[g][q], hp[q], a1);
        racc[g] = (__low2float(a0) + __high2float(a0)) +
                  (__low2float(a1) + __high2float(a1));
      }
#endif

      // add pre (each lane of the pair contributes 2 gates), then pair-reduce
      if (kh == 0) { racc[0] += paF; racc[1] += pbF; }
      else         { racc[2] += paF; racc[3] += pbF; }
#pragma unroll
      for (int g = 0; g < 4; g++) racc[g] += __shfl_xor(racc[g], 1);

      // activations (both lanes of the pair compute identically; no divergence)
      float ig = sigm(racc[0]), fg = sigm(racc[1]);
      float g2 = tanh_fast(racc[2]), og = sigm(racc[3]);
      c = fg * c + ig * g2;
      float h = og * tanh_fast(c);

      if (act && kh == 0) {
        int seg = (j >= 50) ? 1 : 0;
        hsh[cur ^ 1][seg][j - seg * 50] = (_Float16)h;
        *hptr = (_Float16)h;
      }

      barrier_lds_only();
      cur ^= 1;
      preOff += pdelta;
      hptr += hstep;
    }
  }
#undef GSRC
}

// ---------------- K4: emission = [h_f,h_b] @ proj_w^T + proj_b ----------------
__global__ __launch_bounds__(256) void k_proj(const _Float16* __restrict__ hbuf,
                                              const float* __restrict__ pw,
                                              const float* __restrict__ pb,
                                              float* __restrict__ em) {
  __shared__ __align__(16) float pws[NTAGS * 204];   // 25.9 KB
  __shared__ float pbs[NTAGS];
  int tid = threadIdx.x;
  for (int i = tid; i < NTAGS * 2 * HDIM; i += 256) {
    int tag = i / (2 * HDIM);
    int k = i - tag * (2 * HDIM);
    pws[tag * 204 + k] = pw[i];
  }
  if (tid < NTAGS) pbs[tid] = pb[tid];
  __syncthreads();

  int idx = blockIdx.x * blockDim.x + tid;  // token*32 + tag
  if (idx >= BB * SS * NTAGS) return;
  int token = idx >> 5, tag = idx & 31;
  const uint4* h4 = (const uint4*)(hbuf + (size_t)token * 2 * HDIM);
  const float4* w4 = (const float4*)&pws[tag * 204];
  float acc = pbs[tag];
#pragma unroll
  for (int k = 0; k < 25; k++) {
    uint4 hv = h4[k];
    h2 a = __builtin_bit_cast(h2, hv.x);
    h2 bq = __builtin_bit_cast(h2, hv.y);
    h2 cq = __builtin_bit_cast(h2, hv.z);
    h2 d = __builtin_bit_cast(h2, hv.w);
    float4 w0 = w4[k * 2], w1 = w4[k * 2 + 1];
    acc += (float)a.x * w0.x + (float)a.y * w0.y + (float)bq.x * w0.z + (float)bq.y * w0.w
         + (float)cq.x * w1.x + (float)cq.y * w1.y + (float)d.x * w1.z + (float)d.y * w1.w;
  }
  em[idx] = acc;
}

// ---------------- K5: CRF forward + gold score + loss (R21: LDS-staged em) ----------------
// Same exposed-vmcnt theory as k_lstm: the per-step rolling e0/e1/e2 global
// prefetch serializes on in-flight loads. em[b] is only 32 KB -> stage the
// whole thing (plus mask) into LDS up front; the 256-step loop is then pure
// LDS/VALU. Math and summation order unchanged.
__global__ __launch_bounds__(64) void k_crf(const float* __restrict__ em,
                                            const float* __restrict__ trans,
                                            const int* __restrict__ mask,
                                            const int* __restrict__ y,
                                            float* __restrict__ out) {
  int b = blockIdx.x;
  int lane = threadIdx.x;
  int j = lane & 31;
  int h = lane >> 5;

  __shared__ __align__(16) float emS[SS * NTAGS];   // 32 KB
  __shared__ __align__(16) int mkS[SS];             // 1 KB
  {
    const uint4* src = (const uint4*)(em + (size_t)b * SS * NTAGS);
#pragma unroll
    for (int p = 0; p < 32; p++) {
      uint4 t = src[p * 64 + lane];
      *(uint4*)&emS[(p * 64 + lane) * 4] = t;
    }
    uint4 mv = ((const uint4*)(mask + (size_t)b * SS))[lane];
    *(uint4*)&mkS[lane * 4] = mv;
  }
  barrier_lds_only();

  // ---- gold path score, 64 lanes (em from LDS now) ----
  float sacc = 0.f;
  for (int s = lane; s < SS; s += 64) {
    int curt = y[b * SS + s];
    int prevt = (s == 0) ? TAG_START : y[b * SS + s - 1];
    float mk = (float)mkS[s];
    sacc += (emS[s * NTAGS + curt] + trans[prevt * NTAGS + curt]) * mk;
  }
#pragma unroll
  for (int off = 32; off > 0; off >>= 1) sacc += __shfl_down(sacc, off);
  float scoreYv = __shfl(sacc, 0) + trans[y[b * SS + SS - 1] * NTAGS + TAG_END];

  float tcol[16];
#pragma unroll
  for (int i = 0; i < 16; i++) tcol[i] = trans[(h * 16 + i) * NTAGS + j];

  float la = (j == TAG_START) ? 0.f : NEGV;

  for (int s = 0; s < SS; s++) {
    float e0 = emS[s * NTAGS + j];
    float mkv = (float)mkS[s];

    float v[16];
#pragma unroll
    for (int i = 0; i < 16; i++) v[i] = __shfl(la, h * 16 + i) + tcol[i];

    float ma = v[0], mb2 = v[1];
#pragma unroll
    for (int i = 2; i < 16; i += 2) { ma = fmaxf(ma, v[i]); mb2 = fmaxf(mb2, v[i + 1]); }
    float mh = fmaxf(ma, mb2);
    float m = fmaxf(mh, __shfl_xor(mh, 32));

    float sa = 0.f, sb = 0.f;
#pragma unroll
    for (int i = 0; i < 16; i += 2) { sa += __expf(v[i] - m); sb += __expf(v[i + 1] - m); }
    float sh = sa + sb;
    float sum = sh + __shfl_xor(sh, 32);

    float la2 = m + __logf(sum) + e0;
    la = la2 * mkv + la * (1.f - mkv);
  }
  la += trans[j * NTAGS + TAG_END];

  float mm = la;
#pragma unroll
  for (int off = 16; off > 0; off >>= 1) mm = fmaxf(mm, __shfl_xor(mm, off));
  float ss = __expf(la - mm);
#pragma unroll
  for (int off = 16; off > 0; off >>= 1) ss += __shfl_xor(ss, off);
  float total = mm + __logf(ss);
  if (lane == 0) atomicAdd(out, (total - scoreYv) * (1.0f / BB));
}

extern "C" void kernel_launch(void* const* d_in, const int* in_sizes, int n_in,
                              void* d_out, int out_size, void* d_ws, size_t ws_size,
                              hipStream_t stream) {
  const float* word_emb = (const float*)d_in[0];
  const float* char_emb = (const float*)d_in[1];
  const float* conv_w   = (const float*)d_in[2];
  const float* conv_b   = (const float*)d_in[3];
  const float* wih_f    = (const float*)d_in[4];
  const float* whh_f    = (const float*)d_in[5];
  const float* bih_f    = (const float*)d_in[6];
  const float* bhh_f    = (const float*)d_in[7];
  const float* wih_b    = (const float*)d_in[8];
  const float* whh_b    = (const float*)d_in[9];
  const float* bih_b    = (const float*)d_in[10];
  const float* bhh_b    = (const float*)d_in[11];
  const float* proj_w   = (const float*)d_in[12];
  const float* proj_b   = (const float*)d_in[13];
  const float* trans    = (const float*)d_in[14];
  const int* word_x     = (const int*)d_in[15];
  const int* char_x     = (const int*)d_in[16];
  const int* y          = (const int*)d_in[17];
  const int* mask       = (const int*)d_in[18];
  float* out = (float*)d_out;

  _Float16* x16   = (_Float16*)d_ws;                     // 32768*160 halves
  _Float16* w16   = x16 + (size_t)BB * SS * KPAD;        // 832*160 halves
  _Float16* preF  = w16 + (size_t)NROWS * KPAD;          // 32768*400 halves
  _Float16* preB  = preF + (size_t)BB * SS * GDIM;       // 32768*400 halves
  _Float16* hbuf  = preB + (size_t)BB * SS * GDIM;       // 32768*200 halves
  float* em       = (float*)(hbuf + (size_t)BB * SS * 2 * HDIM);  // 32768*32 f32

  k_pre<<<NB_PRE, 256, 0, stream>>>(word_emb, word_x, char_emb, conv_w, conv_b,
                                    char_x, wih_f, wih_b, x16, w16, out);
  k_pregemm<<<dim3(BB * SS / 64, 13), 256, 0, stream>>>(x16, w16, bih_f, bhh_f,
                                                        bih_b, bhh_b, preF, preB);
  k_lstm<<<256, 256, 0, stream>>>(preF, preB, whh_f, whh_b, hbuf);
  k_proj<<<(BB * SS * NTAGS + 255) / 256, 256, 0, stream>>>(hbuf, proj_w, proj_b, em);
  k_crf<<<BB, 64, 0, stream>>>(em, trans, mask, y, out);
}